// Round 7
// baseline (143.482 us; speedup 1.0000x reference)
//
#include <hip/hip_runtime.h>
#include <hip/hip_fp16.h>

// out[e] = dot(h[src[e]], h[dst[e]]), D=128, N=100k, E=600k.
// Round-6 counters: random-gather kernel pinned at 3.3 TB/s on the L2-miss
// path, identical across MLP depths -> throughput wall on random misses
// (per-XCD footprint 25.6MB >> 4MB L2). This round: D-sliced partials.
//   hsl[8][N][16] fp16 slabs (3.2MB each, fits one XCD's L2).
//   partial_dot: slice s = blockIdx&7 (round-robins onto XCD s): all gathers
//   of slab s stay in that XCD's L2 -> miss stream ~compulsory only.
//   2 lanes/edge: each lane loads one uint4 (8 halves); 32B row-slice is one
//   coalesced segment. fdot2 accumulate, 1 shfl to pair up, partial[s][e].
//   reduce8: out[e] = sum_s partial[s][e].

constexpr int D      = 128;
constexpr int NSLICE = 8;
constexpr int SW     = 16;    // halves per slice
constexpr int CHUNKS = 256;   // edge chunks; grid = 8*CHUNKS = 2048 blocks

#if defined(__has_builtin)
#if __has_builtin(__builtin_amdgcn_fdot2)
#define HAS_FDOT2 1
#endif
#endif
#ifndef HAS_FDOT2
#define HAS_FDOT2 0
#endif

__device__ __forceinline__ unsigned packh2(float x, float y) {
    __half2 p = __floats2half2_rn(x, y);
    return *reinterpret_cast<unsigned*>(&p);
}

__device__ __forceinline__ float fdot2acc(unsigned a, unsigned b, float acc) {
    __half2 ha = *reinterpret_cast<__half2*>(&a);
    __half2 hb = *reinterpret_cast<__half2*>(&b);
#if HAS_FDOT2
    return __builtin_amdgcn_fdot2(*reinterpret_cast<_Float16_2*>(&ha),
                                  *reinterpret_cast<_Float16_2*>(&hb),
                                  acc, false);
#else
    float2 fa = __half22float2(ha);
    float2 fb = __half22float2(hb);
    return fmaf(fa.y, fb.y, fmaf(fa.x, fb.x, acc));
#endif
}

__device__ __forceinline__ float dot8u(uint4 a, uint4 b) {
    float acc = 0.f;
    acc = fdot2acc(a.x, b.x, acc);
    acc = fdot2acc(a.y, b.y, acc);
    acc = fdot2acc(a.z, b.z, acc);
    acc = fdot2acc(a.w, b.w, acc);
    return acc;
}

// ---------- K1: h [N][128] f32 -> hsl [8][N][16] f16 slabs ----------
// task = (n, s): read h[n][16s..16s+16) (64B, wave-contiguous across tasks),
// write 32B to slab s at node n (per-s segments of 256B across the wave).
__global__ __launch_bounds__(256) void convert_slice_kernel(
    const float* __restrict__ h, __half* __restrict__ hsl, int N)
{
    const int total  = N * NSLICE;
    const int stride = gridDim.x * blockDim.x;
    for (int task = blockIdx.x * blockDim.x + threadIdx.x; task < total; task += stride) {
        const int n = task >> 3;
        const int s = task & 7;
        const float4* srow = reinterpret_cast<const float4*>(h + (size_t)n * D + s * SW);
        float4 v0 = srow[0], v1 = srow[1], v2 = srow[2], v3 = srow[3];
        uint4 w0, w1;
        w0.x = packh2(v0.x, v0.y); w0.y = packh2(v0.z, v0.w);
        w0.z = packh2(v1.x, v1.y); w0.w = packh2(v1.z, v1.w);
        w1.x = packh2(v2.x, v2.y); w1.y = packh2(v2.z, v2.w);
        w1.z = packh2(v3.x, v3.y); w1.w = packh2(v3.z, v3.w);
        uint4* drow = reinterpret_cast<uint4*>(hsl + ((size_t)s * N + n) * SW);
        drow[0] = w0;
        drow[1] = w1;
    }
}

// ---------- K2: sliced partial dots ----------
// blockIdx = c*8 + s  ->  slice s lands on XCD s (round-robin dispatch).
// 2 lanes per edge: lane j in {0,1} covers dims [8j..8j+8) of the slice.
__global__ __launch_bounds__(256) void partial_dot_kernel(
    const __half* __restrict__ hsl,
    const int*    __restrict__ src,
    const int*    __restrict__ dst,
    float*        __restrict__ partial,
    int E, int N, int chunk)
{
    const int s = blockIdx.x & (NSLICE - 1);
    const int c = blockIdx.x >> 3;
    const __half* __restrict__ base = hsl + (size_t)s * N * SW;
    float* __restrict__ pout = partial + (size_t)s * E;

    const int start = c * chunk;
    const int end   = (start + chunk < E) ? (start + chunk) : E;
    const int lp    = threadIdx.x >> 1;     // pair id within block (0..127)
    const int j     = threadIdx.x & 1;      // half-slice 0/1
    const int PSTR  = 128;                  // pairs per block
    const int joff  = j * 8;                // halves offset (16B)

    int e = start + lp;
    // 2-edge unroll: 4 independent 16B gathers + 4 idx loads in flight.
    for (; e + PSTR < end; e += 2 * PSTR) {
        const int e2 = e + PSTR;
        const int s1 = src[e],  t1 = dst[e];
        const int s2 = src[e2], t2 = dst[e2];
        uint4 a1 = *reinterpret_cast<const uint4*>(base + (size_t)s1 * SW + joff);
        uint4 b1 = *reinterpret_cast<const uint4*>(base + (size_t)t1 * SW + joff);
        uint4 a2 = *reinterpret_cast<const uint4*>(base + (size_t)s2 * SW + joff);
        uint4 b2 = *reinterpret_cast<const uint4*>(base + (size_t)t2 * SW + joff);
        float d1 = dot8u(a1, b1);
        float d2 = dot8u(a2, b2);
        d1 += __shfl_xor(d1, 1);
        d2 += __shfl_xor(d2, 1);
        if (j == 0) {
            pout[e]  = d1;
            pout[e2] = d2;
        }
    }
    for (; e < end; e += PSTR) {
        const int s1 = src[e], t1 = dst[e];
        uint4 a1 = *reinterpret_cast<const uint4*>(base + (size_t)s1 * SW + joff);
        uint4 b1 = *reinterpret_cast<const uint4*>(base + (size_t)t1 * SW + joff);
        float d1 = dot8u(a1, b1);
        d1 += __shfl_xor(d1, 1);
        if (j == 0) pout[e] = d1;
    }
}

// ---------- K3: out[e] = sum_s partial[s][e] ----------
__global__ __launch_bounds__(256) void reduce8_kernel(
    const float* __restrict__ partial, float* __restrict__ out, int E)
{
    const int stride = gridDim.x * blockDim.x;
    if ((E & 3) == 0) {
        const int n4 = E >> 2;
        for (int i = blockIdx.x * blockDim.x + threadIdx.x; i < n4; i += stride) {
            float4 acc = reinterpret_cast<const float4*>(partial)[i];
#pragma unroll
            for (int s = 1; s < NSLICE; ++s) {
                float4 p = reinterpret_cast<const float4*>(partial + (size_t)s * E)[i];
                acc.x += p.x; acc.y += p.y; acc.z += p.z; acc.w += p.w;
            }
            reinterpret_cast<float4*>(out)[i] = acc;
        }
    } else {
        for (int i = blockIdx.x * blockDim.x + threadIdx.x; i < E; i += stride) {
            float acc = 0.f;
#pragma unroll
            for (int s = 0; s < NSLICE; ++s) acc += partial[(size_t)s * E + i];
            out[i] = acc;
        }
    }
}

// ---------- fallbacks (proven round-6 path) ----------
constexpr int LPE = 16;

__global__ __launch_bounds__(256) void convert_kernel(
    const float* __restrict__ h, __half* __restrict__ hh, int n4)
{
    const int stride = gridDim.x * blockDim.x;
    for (int k = blockIdx.x * blockDim.x + threadIdx.x; k < n4; k += stride) {
        float4 v = reinterpret_cast<const float4*>(h)[k];
        uint2 packed;
        packed.x = packh2(v.x, v.y);
        packed.y = packh2(v.z, v.w);
        reinterpret_cast<uint2*>(hh)[k] = packed;
    }
}

__device__ __forceinline__ float reduce16(float acc)
{
    acc += __shfl_xor(acc, 1);
    acc += __shfl_xor(acc, 2);
    acc += __shfl_xor(acc, 4);
    acc += __shfl_xor(acc, 8);
    return acc;
}

__global__ __launch_bounds__(256) void edge_dot_f16_kernel(
    const __half* __restrict__ hh,
    const int*    __restrict__ src,
    const int*    __restrict__ dst,
    float*        __restrict__ out,
    int E)
{
    const int tid    = blockIdx.x * blockDim.x + threadIdx.x;
    const int sub    = threadIdx.x & (LPE - 1);
    const int slot   = tid / LPE;
    const int nslots = (gridDim.x * blockDim.x) / LPE;

    for (int e = slot; e < E; e += nslots) {
        const int ss = src[e];
        const int tt = dst[e];
        uint4 a = *(reinterpret_cast<const uint4*>(hh + (size_t)ss * D) + sub);
        uint4 b = *(reinterpret_cast<const uint4*>(hh + (size_t)tt * D) + sub);
        float acc = reduce16(dot8u(a, b));
        if (sub == 0) out[e] = acc;
    }
}

__global__ __launch_bounds__(256) void edge_dot_f32_kernel(
    const float* __restrict__ h,
    const int*   __restrict__ src,
    const int*   __restrict__ dst,
    float*       __restrict__ out,
    int E)
{
    const int tid    = blockIdx.x * blockDim.x + threadIdx.x;
    const int sub    = threadIdx.x & (LPE - 1);
    const int slot   = tid / LPE;
    const int nslots = (gridDim.x * blockDim.x) / LPE;
    const int off    = sub * 2;

    for (int e = slot; e < E; e += nslots) {
        const int s = src[e];
        const int t = dst[e];
        const float4* hu = reinterpret_cast<const float4*>(h + (size_t)s * D) + off;
        const float4* hv = reinterpret_cast<const float4*>(h + (size_t)t * D) + off;
        float4 a0 = hu[0]; float4 a1 = hu[1];
        float4 b0 = hv[0]; float4 b1 = hv[1];
        float acc = a0.x * b0.x + a0.y * b0.y + a0.z * b0.z + a0.w * b0.w
                  + a1.x * b1.x + a1.y * b1.y + a1.z * b1.z + a1.w * b1.w;
        acc = reduce16(acc);
        if (sub == 0) out[e] = acc;
    }
}

extern "C" void kernel_launch(void* const* d_in, const int* in_sizes, int n_in,
                              void* d_out, int out_size, void* d_ws, size_t ws_size,
                              hipStream_t stream) {
    const float* h   = (const float*)d_in[0];
    const int*   src = (const int*)d_in[1];
    const int*   dst = (const int*)d_in[2];
    float*       out = (float*)d_out;

    const int hN = in_sizes[0];      // N*D floats
    const int E  = in_sizes[1];      // edges
    const int N  = hN / D;

    const size_t slabBytes = ((size_t)hN * sizeof(__half) + 15) & ~(size_t)15;
    const size_t partBytes = (size_t)NSLICE * E * sizeof(float);

    if (ws_size >= slabBytes + partBytes) {
        __half* hsl     = (__half*)d_ws;
        float*  partial = (float*)((char*)d_ws + slabBytes);

        convert_slice_kernel<<<2048, 256, 0, stream>>>(h, hsl, N);
        const int chunk = (E + CHUNKS - 1) / CHUNKS;
        partial_dot_kernel<<<NSLICE * CHUNKS, 256, 0, stream>>>(
            hsl, src, dst, partial, E, N, chunk);
        reduce8_kernel<<<1024, 256, 0, stream>>>(partial, out, E);
    } else if (ws_size >= (size_t)hN * sizeof(__half)) {
        __half* hh = (__half*)d_ws;
        convert_kernel<<<2048, 256, 0, stream>>>(h, hh, hN / 4);
        int grid = (E + (256 / LPE) - 1) / (256 / LPE);
        if (grid > 2048) grid = 2048;
        edge_dot_f16_kernel<<<grid, 256, 0, stream>>>(hh, src, dst, out, E);
    } else {
        int grid = (E + (256 / LPE) - 1) / (256 / LPE);
        if (grid > 2048) grid = 2048;
        edge_dot_f32_kernel<<<grid, 256, 0, stream>>>(h, src, dst, out, E);
    }
}

// Round 8
// 139.968 us; speedup vs baseline: 1.0251x; 1.0251x over previous
//
#include <hip/hip_runtime.h>
#include <hip/hip_fp16.h>

// out[e] = dot(h[src[e]], h[dst[e]]), D=128, N=100k, E=600k.
// Model (fits r4/r6/r7 counters): random-gather time ~ lines/CU * latency / MSHR.
// r7 (8 slices, 32B rows): 9.6M lines @ L2-hit latency -> 53us.
// r6 (full 256B rows):     4.8M lines @ L3-ish latency -> 42us.
// This round: 4 slices x 32 dims fp16 -> 64B rows = 1 fully-used line per
// edge-row-slice: compulsory-minimum 4.8M lines AND mostly-L2 latency
// (slab 6.4MB vs 4MB L2/XCD, ~60% hit). slice = blockIdx&3 -> XCD x serves
// slice x&3 (round-robin dispatch). 4 lanes/edge, fdot2, 2x shfl_xor.

constexpr int D      = 128;
constexpr int NSLICE = 4;
constexpr int SW     = 32;    // halves per slice (64B rows)
constexpr int CHUNKS = 512;   // grid = 4*CHUNKS = 2048 blocks

#if defined(__has_builtin)
#if __has_builtin(__builtin_amdgcn_fdot2)
#define HAS_FDOT2 1
#endif
#endif
#ifndef HAS_FDOT2
#define HAS_FDOT2 0
#endif

__device__ __forceinline__ unsigned packh2(float x, float y) {
    __half2 p = __floats2half2_rn(x, y);
    return *reinterpret_cast<unsigned*>(&p);
}

__device__ __forceinline__ float fdot2acc(unsigned a, unsigned b, float acc) {
    __half2 ha = *reinterpret_cast<__half2*>(&a);
    __half2 hb = *reinterpret_cast<__half2*>(&b);
#if HAS_FDOT2
    return __builtin_amdgcn_fdot2(*reinterpret_cast<_Float16_2*>(&ha),
                                  *reinterpret_cast<_Float16_2*>(&hb),
                                  acc, false);
#else
    float2 fa = __half22float2(ha);
    float2 fb = __half22float2(hb);
    return fmaf(fa.y, fb.y, fmaf(fa.x, fb.x, acc));
#endif
}

__device__ __forceinline__ float dot8u(uint4 a, uint4 b) {
    float acc = 0.f;
    acc = fdot2acc(a.x, b.x, acc);
    acc = fdot2acc(a.y, b.y, acc);
    acc = fdot2acc(a.z, b.z, acc);
    acc = fdot2acc(a.w, b.w, acc);
    return acc;
}

// ---------- K1: h [N][128] f32 -> hsl [4][N][32] f16 slabs ----------
__global__ __launch_bounds__(256) void convert_slice_kernel(
    const float* __restrict__ h, __half* __restrict__ hsl, int N)
{
    const int total  = N * NSLICE;
    const int stride = gridDim.x * blockDim.x;
    for (int task = blockIdx.x * blockDim.x + threadIdx.x; task < total; task += stride) {
        const int n = task >> 2;
        const int s = task & 3;
        const float4* srow = reinterpret_cast<const float4*>(h + (size_t)n * D + s * SW);
        uint4* drow = reinterpret_cast<uint4*>(hsl + ((size_t)s * N + n) * SW);
#pragma unroll
        for (int half = 0; half < 2; ++half) {
            float4 v0 = srow[half * 4 + 0], v1 = srow[half * 4 + 1];
            float4 v2 = srow[half * 4 + 2], v3 = srow[half * 4 + 3];
            uint4 w0, w1;
            w0.x = packh2(v0.x, v0.y); w0.y = packh2(v0.z, v0.w);
            w0.z = packh2(v1.x, v1.y); w0.w = packh2(v1.z, v1.w);
            w1.x = packh2(v2.x, v2.y); w1.y = packh2(v2.z, v2.w);
            w1.z = packh2(v3.x, v3.y); w1.w = packh2(v3.z, v3.w);
            drow[half * 2 + 0] = w0;
            drow[half * 2 + 1] = w1;
        }
    }
}

// ---------- K2: sliced partial dots ----------
// blockIdx = c*4 + s; XCD = blockIdx%8 -> XCD x serves slice x&3.
// 4 lanes/edge: lane j covers halves [8j..8j+8) of the 32-half slice.
__global__ __launch_bounds__(256) void partial_dot_kernel(
    const __half* __restrict__ hsl,
    const int*    __restrict__ src,
    const int*    __restrict__ dst,
    float*        __restrict__ partial,
    int E, int N, int chunk)
{
    const int s = blockIdx.x & (NSLICE - 1);
    const int c = blockIdx.x >> 2;
    const __half* __restrict__ base = hsl + (size_t)s * N * SW;
    float* __restrict__ pout = partial + (size_t)s * E;

    const int start = c * chunk;
    const int end   = (start + chunk < E) ? (start + chunk) : E;
    const int lp    = threadIdx.x >> 2;     // edge-slot within block (0..63)
    const int j     = threadIdx.x & 3;      // quarter-slice 0..3
    const int PSTR  = 64;                   // edge slots per block
    const int joff  = j * 8;                // halves offset (16B)

    int e = start + lp;
    // 2-edge unroll: 4 independent 16B gathers in flight per lane.
    for (; e + PSTR < end; e += 2 * PSTR) {
        const int e2 = e + PSTR;
        const int s1 = src[e],  t1 = dst[e];
        const int s2 = src[e2], t2 = dst[e2];
        uint4 a1 = *reinterpret_cast<const uint4*>(base + (size_t)s1 * SW + joff);
        uint4 b1 = *reinterpret_cast<const uint4*>(base + (size_t)t1 * SW + joff);
        uint4 a2 = *reinterpret_cast<const uint4*>(base + (size_t)s2 * SW + joff);
        uint4 b2 = *reinterpret_cast<const uint4*>(base + (size_t)t2 * SW + joff);
        float d1 = dot8u(a1, b1);
        float d2 = dot8u(a2, b2);
        d1 += __shfl_xor(d1, 1);
        d1 += __shfl_xor(d1, 2);
        d2 += __shfl_xor(d2, 1);
        d2 += __shfl_xor(d2, 2);
        if (j == 0) {
            pout[e]  = d1;
            pout[e2] = d2;
        }
    }
    for (; e < end; e += PSTR) {
        const int s1 = src[e], t1 = dst[e];
        uint4 a1 = *reinterpret_cast<const uint4*>(base + (size_t)s1 * SW + joff);
        uint4 b1 = *reinterpret_cast<const uint4*>(base + (size_t)t1 * SW + joff);
        float d1 = dot8u(a1, b1);
        d1 += __shfl_xor(d1, 1);
        d1 += __shfl_xor(d1, 2);
        if (j == 0) pout[e] = d1;
    }
}

// ---------- K3: out[e] = sum_s partial[s][e] ----------
__global__ __launch_bounds__(256) void reduce4_kernel(
    const float* __restrict__ partial, float* __restrict__ out, int E)
{
    const int stride = gridDim.x * blockDim.x;
    if ((E & 3) == 0) {
        const int n4 = E >> 2;
        for (int i = blockIdx.x * blockDim.x + threadIdx.x; i < n4; i += stride) {
            float4 acc = reinterpret_cast<const float4*>(partial)[i];
#pragma unroll
            for (int s = 1; s < NSLICE; ++s) {
                float4 p = reinterpret_cast<const float4*>(partial + (size_t)s * E)[i];
                acc.x += p.x; acc.y += p.y; acc.z += p.z; acc.w += p.w;
            }
            reinterpret_cast<float4*>(out)[i] = acc;
        }
    } else {
        for (int i = blockIdx.x * blockDim.x + threadIdx.x; i < E; i += stride) {
            float acc = 0.f;
#pragma unroll
            for (int s = 0; s < NSLICE; ++s) acc += partial[(size_t)s * E + i];
            out[i] = acc;
        }
    }
}

// ---------- fallbacks (proven round-6 path) ----------
constexpr int LPE = 16;

__global__ __launch_bounds__(256) void convert_kernel(
    const float* __restrict__ h, __half* __restrict__ hh, int n4)
{
    const int stride = gridDim.x * blockDim.x;
    for (int k = blockIdx.x * blockDim.x + threadIdx.x; k < n4; k += stride) {
        float4 v = reinterpret_cast<const float4*>(h)[k];
        uint2 packed;
        packed.x = packh2(v.x, v.y);
        packed.y = packh2(v.z, v.w);
        reinterpret_cast<uint2*>(hh)[k] = packed;
    }
}

__device__ __forceinline__ float reduce16(float acc)
{
    acc += __shfl_xor(acc, 1);
    acc += __shfl_xor(acc, 2);
    acc += __shfl_xor(acc, 4);
    acc += __shfl_xor(acc, 8);
    return acc;
}

__global__ __launch_bounds__(256) void edge_dot_f16_kernel(
    const __half* __restrict__ hh,
    const int*    __restrict__ src,
    const int*    __restrict__ dst,
    float*        __restrict__ out,
    int E)
{
    const int tid    = blockIdx.x * blockDim.x + threadIdx.x;
    const int sub    = threadIdx.x & (LPE - 1);
    const int slot   = tid / LPE;
    const int nslots = (gridDim.x * blockDim.x) / LPE;

    for (int e = slot; e < E; e += nslots) {
        const int ss = src[e];
        const int tt = dst[e];
        uint4 a = *(reinterpret_cast<const uint4*>(hh + (size_t)ss * D) + sub);
        uint4 b = *(reinterpret_cast<const uint4*>(hh + (size_t)tt * D) + sub);
        float acc = reduce16(dot8u(a, b));
        if (sub == 0) out[e] = acc;
    }
}

__global__ __launch_bounds__(256) void edge_dot_f32_kernel(
    const float* __restrict__ h,
    const int*   __restrict__ src,
    const int*   __restrict__ dst,
    float*       __restrict__ out,
    int E)
{
    const int tid    = blockIdx.x * blockDim.x + threadIdx.x;
    const int sub    = threadIdx.x & (LPE - 1);
    const int slot   = tid / LPE;
    const int nslots = (gridDim.x * blockDim.x) / LPE;
    const int off    = sub * 2;

    for (int e = slot; e < E; e += nslots) {
        const int s = src[e];
        const int t = dst[e];
        const float4* hu = reinterpret_cast<const float4*>(h + (size_t)s * D) + off;
        const float4* hv = reinterpret_cast<const float4*>(h + (size_t)t * D) + off;
        float4 a0 = hu[0]; float4 a1 = hu[1];
        float4 b0 = hv[0]; float4 b1 = hv[1];
        float acc = a0.x * b0.x + a0.y * b0.y + a0.z * b0.z + a0.w * b0.w
                  + a1.x * b1.x + a1.y * b1.y + a1.z * b1.z + a1.w * b1.w;
        acc = reduce16(acc);
        if (sub == 0) out[e] = acc;
    }
}

extern "C" void kernel_launch(void* const* d_in, const int* in_sizes, int n_in,
                              void* d_out, int out_size, void* d_ws, size_t ws_size,
                              hipStream_t stream) {
    const float* h   = (const float*)d_in[0];
    const int*   src = (const int*)d_in[1];
    const int*   dst = (const int*)d_in[2];
    float*       out = (float*)d_out;

    const int hN = in_sizes[0];      // N*D floats
    const int E  = in_sizes[1];      // edges
    const int N  = hN / D;

    const size_t slabBytes = ((size_t)hN * sizeof(__half) + 255) & ~(size_t)255;
    const size_t partBytes = (size_t)NSLICE * E * sizeof(float);

    if (ws_size >= slabBytes + partBytes) {
        __half* hsl     = (__half*)d_ws;
        float*  partial = (float*)((char*)d_ws + slabBytes);

        convert_slice_kernel<<<2048, 256, 0, stream>>>(h, hsl, N);
        const int chunk = (E + CHUNKS - 1) / CHUNKS;
        partial_dot_kernel<<<NSLICE * CHUNKS, 256, 0, stream>>>(
            hsl, src, dst, partial, E, N, chunk);
        reduce4_kernel<<<1024, 256, 0, stream>>>(partial, out, E);
    } else if (ws_size >= (size_t)hN * sizeof(__half)) {
        __half* hh = (__half*)d_ws;
        convert_kernel<<<2048, 256, 0, stream>>>(h, hh, hN / 4);
        int grid = (E + (256 / LPE) - 1) / (256 / LPE);
        if (grid > 2048) grid = 2048;
        edge_dot_f16_kernel<<<grid, 256, 0, stream>>>(hh, src, dst, out, E);
    } else {
        int grid = (E + (256 / LPE) - 1) / (256 / LPE);
        if (grid > 2048) grid = 2048;
        edge_dot_f32_kernel<<<grid, 256, 0, stream>>>(h, src, dst, out, E);
    }
}

// Round 9
// 130.278 us; speedup vs baseline: 1.1014x; 1.0744x over previous
//
#include <hip/hip_runtime.h>
#include <hip/hip_fp16.h>

// out[e] = dot(h[src[e]], h[dst[e]]), D=128, N=100k, E=600k.
// Final structure (best measured end-to-end: 129.9us r4 / 131.3us r6):
//   K1: h fp32 -> fp16 (halves gather bytes; footprint 25.6MB).
//   K2: 16 lanes/edge, each lane one uint4 (8 halves) -> full 256B row is
//       one coalesced 4-line burst; 2-edge unroll; fdot2 accumulate in fp32;
//       4x shfl_xor reduce.
// Measured wall (r6/r7/r8 triangulation): random-gather miss path pins at
// ~3.4 TB/s (64B-granule) and ~1.4ns/line/CU request throughput. D-slicing
// for XCD-L2 affinity traded between the two walls with no net win; the
// extra partial/reduce kernels lost end-to-end. This is the simple point on
// the wall.

constexpr int D   = 128;
constexpr int LPE = 16;   // lanes per edge

#if defined(__has_builtin)
#if __has_builtin(__builtin_amdgcn_fdot2)
#define HAS_FDOT2 1
#endif
#endif
#ifndef HAS_FDOT2
#define HAS_FDOT2 0
#endif

__device__ __forceinline__ unsigned packh2(float x, float y) {
    __half2 p = __floats2half2_rn(x, y);
    return *reinterpret_cast<unsigned*>(&p);
}

__device__ __forceinline__ float fdot2acc(unsigned a, unsigned b, float acc) {
    __half2 ha = *reinterpret_cast<__half2*>(&a);
    __half2 hb = *reinterpret_cast<__half2*>(&b);
#if HAS_FDOT2
    return __builtin_amdgcn_fdot2(*reinterpret_cast<_Float16_2*>(&ha),
                                  *reinterpret_cast<_Float16_2*>(&hb),
                                  acc, false);
#else
    float2 fa = __half22float2(ha);
    float2 fb = __half22float2(hb);
    return fmaf(fa.y, fb.y, fmaf(fa.x, fb.x, acc));
#endif
}

__device__ __forceinline__ float dot8u(uint4 a, uint4 b) {
    float acc = 0.f;
    acc = fdot2acc(a.x, b.x, acc);
    acc = fdot2acc(a.y, b.y, acc);
    acc = fdot2acc(a.z, b.z, acc);
    acc = fdot2acc(a.w, b.w, acc);
    return acc;
}

__device__ __forceinline__ float reduce16(float acc)
{
    acc += __shfl_xor(acc, 1);
    acc += __shfl_xor(acc, 2);
    acc += __shfl_xor(acc, 4);
    acc += __shfl_xor(acc, 8);
    return acc;
}

// ---------- K1: h (fp32) -> hh (fp16), streaming, BW-limited ----------
__global__ __launch_bounds__(256) void convert_kernel(
    const float* __restrict__ h, __half* __restrict__ hh, int n4)
{
    const int stride = gridDim.x * blockDim.x;
    for (int k = blockIdx.x * blockDim.x + threadIdx.x; k < n4; k += stride) {
        float4 v = reinterpret_cast<const float4*>(h)[k];
        uint2 packed;
        packed.x = packh2(v.x, v.y);
        packed.y = packh2(v.z, v.w);
        reinterpret_cast<uint2*>(hh)[k] = packed;
    }
}

// ---------- K2: fp16 gather + dot ----------
__global__ __launch_bounds__(256) void edge_dot_f16_kernel(
    const __half* __restrict__ hh,
    const int*    __restrict__ src,
    const int*    __restrict__ dst,
    float*        __restrict__ out,
    int E)
{
    const int tid    = blockIdx.x * blockDim.x + threadIdx.x;
    const int sub    = threadIdx.x & (LPE - 1);
    const int slot   = tid / LPE;
    const int nslots = (gridDim.x * blockDim.x) / LPE;

    int e = slot;
    int s1 = 0, t1 = 0, s2 = 0, t2 = 0;
    if (e + nslots < E) {
        s1 = src[e];          t1 = dst[e];
        s2 = src[e + nslots]; t2 = dst[e + nslots];
    }

    while (e + nslots < E) {
        const int e2 = e + nslots;
        const int en = e + 2 * nslots;

        // 4 independent 16B row loads in flight.
        uint4 a = *(reinterpret_cast<const uint4*>(hh + (size_t)s1 * D) + sub);
        uint4 b = *(reinterpret_cast<const uint4*>(hh + (size_t)t1 * D) + sub);
        uint4 c = *(reinterpret_cast<const uint4*>(hh + (size_t)s2 * D) + sub);
        uint4 d = *(reinterpret_cast<const uint4*>(hh + (size_t)t2 * D) + sub);

        // Prefetch next pair's indices while row loads are in flight.
        if (en + nslots < E) {
            s1 = src[en];          t1 = dst[en];
            s2 = src[en + nslots]; t2 = dst[en + nslots];
        }

        float acc1 = reduce16(dot8u(a, b));
        float acc2 = reduce16(dot8u(c, d));

        if (sub == 0) {
            out[e]  = acc1;
            out[e2] = acc2;
        }
        e = en;
    }
    if (e < E) {
        const int ss = src[e];
        const int tt = dst[e];
        uint4 a = *(reinterpret_cast<const uint4*>(hh + (size_t)ss * D) + sub);
        uint4 b = *(reinterpret_cast<const uint4*>(hh + (size_t)tt * D) + sub);
        float acc = reduce16(dot8u(a, b));
        if (sub == 0) out[e] = acc;
    }
}

// ---------- fp32 fallback (no ws) ----------
__global__ __launch_bounds__(256) void edge_dot_f32_kernel(
    const float* __restrict__ h,
    const int*   __restrict__ src,
    const int*   __restrict__ dst,
    float*       __restrict__ out,
    int E)
{
    const int tid    = blockIdx.x * blockDim.x + threadIdx.x;
    const int sub    = threadIdx.x & (LPE - 1);
    const int slot   = tid / LPE;
    const int nslots = (gridDim.x * blockDim.x) / LPE;
    const int off    = sub * 2;

    for (int e = slot; e < E; e += nslots) {
        const int s = src[e];
        const int t = dst[e];
        const float4* hu = reinterpret_cast<const float4*>(h + (size_t)s * D) + off;
        const float4* hv = reinterpret_cast<const float4*>(h + (size_t)t * D) + off;
        float4 a0 = hu[0]; float4 a1 = hu[1];
        float4 b0 = hv[0]; float4 b1 = hv[1];
        float acc = a0.x * b0.x + a0.y * b0.y + a0.z * b0.z + a0.w * b0.w
                  + a1.x * b1.x + a1.y * b1.y + a1.z * b1.z + a1.w * b1.w;
        acc = reduce16(acc);
        if (sub == 0) out[e] = acc;
    }
}

extern "C" void kernel_launch(void* const* d_in, const int* in_sizes, int n_in,
                              void* d_out, int out_size, void* d_ws, size_t ws_size,
                              hipStream_t stream) {
    const float* h   = (const float*)d_in[0];
    const int*   src = (const int*)d_in[1];
    const int*   dst = (const int*)d_in[2];
    float*       out = (float*)d_out;

    const int hN = in_sizes[0];     // N*D floats
    const int E  = in_sizes[1];     // edges

    const int block = 256;
    int grid = (E + (block / LPE) - 1) / (block / LPE);
    if (grid > 2048) grid = 2048;

    const size_t need = (size_t)hN * sizeof(__half);
    if (ws_size >= need) {
        __half* hh = (__half*)d_ws;
        convert_kernel<<<2048, 256, 0, stream>>>(h, hh, hN / 4);
        edge_dot_f16_kernel<<<grid, block, 0, stream>>>(hh, src, dst, out, E);
    } else {
        edge_dot_f32_kernel<<<grid, block, 0, stream>>>(h, src, dst, out, E);
    }
}